// Round 14
// baseline (145.063 us; speedup 1.0000x reference)
//
#include <hip/hip_runtime.h>
#include <math.h>

// Problem constants (B, C, H, W) = (16, 256, 64, 64), GROUPS=4, RATIO=2
#define B_   16
#define C_   256
#define H_   64
#define W_   64
#define G_   4
#define HO_  128
#define WO_  128
#define HW_  (H_ * W_)
#define HOWO_ (HO_ * WO_)

typedef float f4v __attribute__((ext_vector_type(4)));   // NT-store compatible

// Weights in constant address space -> uniform accesses compile to s_load.
__constant__ float wconst[8 * 32 * 40];   // 40 KB

// ---------------------------------------------------------------------------
// Prep: wcomb[u][i2][40] for wave u (v=u&3, hi=u>>2), channel i=64v+32hi+i2:
//   [0..31]  = w_off[o][i]                     o = 0..31
//   [32..39] = w_scope[v][j][32*hi + i2]       j = 0..7
// ---------------------------------------------------------------------------
__global__ __launch_bounds__(256) void prep_kernel(
    const float* __restrict__ w_off,    // (32, 256)
    const float* __restrict__ w_scope,  // (4, 8, 64)
    float* __restrict__ wout)           // = wconst backing store
{
    const int k = blockIdx.x * 256 + threadIdx.x;   // 10240 total
    if (k >= 8 * 32 * 40) return;
    const int q  = k % 40;
    const int r  = k / 40;
    const int i2 = r & 31;
    const int u  = r >> 5;
    const int v  = u & 3;
    const int hi = u >> 2;
    const int i  = 64 * v + 32 * hi + i2;
    float val;
    if (q < 32) val = w_off[q * 256 + i];
    else        val = w_scope[v * 512 + (q - 32) * 64 + 32 * hi + i2];
    wout[k] = val;
}

// ---------------------------------------------------------------------------
// Fused kernel (conv verbatim from R11; sample phase remapped for
// 1-KiB-granule float4 NT stores). Grid = 1024, XCD-bijective swizzle;
// 512 thr = 8 waves. Sample mapping: wave u -> (g = u&3, cc-half = u>>2);
// lane l -> (z = l>>5, wo quad 4*(l&31)). Wave store = 64 lanes x 16 B
// = 1024 B contiguous (rows 2h, 2h+1 adjacent in output layout).
// ---------------------------------------------------------------------------
__global__ __launch_bounds__(512, 6) void fused_kernel(
    const float* __restrict__ x,        // (B, 256, 64, 64)
    const float* __restrict__ b_off,    // (32,)
    const float* __restrict__ b_scope,  // (32,)
    float* __restrict__ out)            // (B, 256, 128, 128)
{
    __shared__ float4 red[8][8][64];    // [slot][chunk][pixel] 32 KB
    __shared__ float4 aux[8][64];       // scp partials, then coords; 8 KB

    const int tid = threadIdx.x;
    const int u   = __builtin_amdgcn_readfirstlane(tid >> 6);  // wave id
    const int w   = tid & 63;                                  // pixel in row

    // XCD-bijective swizzle: XCD k owns b in {2k, 2k+1}, all h.
    const int bid = ((blockIdx.x & 7) << 7) | (blockIdx.x >> 3);
    const int h   = bid & 63;
    const int b   = bid >> 6;

    const int v   = u & 3;              // group (conv)
    const int hi  = u >> 2;             // channel half (conv)

    const float* xq = x + (size_t)b * C_ * HW_ +
                      (size_t)(64 * v + 32 * hi) * HW_ + h * W_ + w;
    const int wbase0 = u * (32 * 40);   // uniform

    float offp[32];
    float scp[8];
#pragma unroll
    for (int j = 0; j < 32; ++j) offp[j] = 0.f;
#pragma unroll
    for (int j = 0; j < 8; ++j) scp[j] = 0.f;

#pragma unroll 4
    for (int i2 = 0; i2 < 32; ++i2) {
        const float xv = xq[(size_t)i2 * HW_];   // coalesced 256 B / wave
        const int wb = wbase0 + i2 * 40;         // uniform -> s_load from AS4
#pragma unroll
        for (int j = 0; j < 32; ++j) offp[j] += xv * wconst[wb + j];
#pragma unroll
        for (int j = 0; j < 8; ++j)  scp[j] += xv * wconst[wb + 32 + j];
    }

    // ---- round 1: high waves publish; low waves absorb pair partner ----
    if (hi) {
#pragma unroll
        for (int j = 0; j < 8; ++j)
            red[4 + v][j][w] = make_float4(offp[4 * j + 0], offp[4 * j + 1],
                                           offp[4 * j + 2], offp[4 * j + 3]);
        aux[2 * v + 0][w] = make_float4(scp[0], scp[1], scp[2], scp[3]);
        aux[2 * v + 1][w] = make_float4(scp[4], scp[5], scp[6], scp[7]);
    }
    __syncthreads();
    if (!hi) {
#pragma unroll
        for (int j = 0; j < 8; ++j) {
            const float4 p = red[4 + v][j][w];
            offp[4 * j + 0] += p.x; offp[4 * j + 1] += p.y;
            offp[4 * j + 2] += p.z; offp[4 * j + 3] += p.w;
        }
        const float4 s0 = aux[2 * v + 0][w];
        const float4 s1 = aux[2 * v + 1][w];
        scp[0] += s0.x; scp[1] += s0.y; scp[2] += s0.z; scp[3] += s0.w;
        scp[4] += s1.x; scp[5] += s1.y; scp[6] += s1.z; scp[7] += s1.w;
        // round 2 publish
#pragma unroll
        for (int j = 0; j < 8; ++j)
            red[v][j][w] = make_float4(offp[4 * j + 0], offp[4 * j + 1],
                                       offp[4 * j + 2], offp[4 * j + 3]);
    }
    __syncthreads();
    if (!hi) {
        float4 a = make_float4(0.f, 0.f, 0.f, 0.f);
        float4 c = make_float4(0.f, 0.f, 0.f, 0.f);
#pragma unroll
        for (int tt = 0; tt < 4; ++tt) {
            const float4 pa = red[tt][2 * v + 0][w];
            const float4 pc = red[tt][2 * v + 1][w];
            a.x += pa.x; a.y += pa.y; a.z += pa.z; a.w += pa.w;
            c.x += pc.x; c.y += pc.y; c.z += pc.z; c.w += pc.w;
        }
        const float ao[8] = {a.x, a.y, a.z, a.w, c.x, c.y, c.z, c.w};
        float f[8];
#pragma unroll
        for (int j = 0; j < 8; ++j) {
            const float offv = ao[j] + b_off[8 * v + j];
            const float scv  = scp[j] + b_scope[8 * v + j];
            f[j] = offv * 0.5f / (1.f + expf(-scv));
        }
        // coords for group v: aux[2v+r1][w] = (ix0,iy0,ix1,iy1) for wo=2w,2w+1
#pragma unroll
        for (int r1 = 0; r1 < 2; ++r1) {
            const float hoF = (float)(2 * h + r1);
            float ix0 = ((float)(2 * w + 0) - 0.5f + f[2 * r1 + 0]) * 0.5f;
            float iy0 = (hoF - 0.5f + f[4 + 2 * r1 + 0]) * 0.5f;
            float ix1 = ((float)(2 * w + 1) - 0.5f + f[2 * r1 + 1]) * 0.5f;
            float iy1 = (hoF - 0.5f + f[4 + 2 * r1 + 1]) * 0.5f;
            ix0 = fminf(fmaxf(ix0, 0.f), (float)(W_ - 1));
            iy0 = fminf(fmaxf(iy0, 0.f), (float)(H_ - 1));
            ix1 = fminf(fmaxf(ix1, 0.f), (float)(W_ - 1));
            iy1 = fminf(fmaxf(iy1, 0.f), (float)(H_ - 1));
            aux[2 * v + r1][w] = make_float4(ix0, iy0, ix1, iy1);
        }
    }
    __syncthreads();

    // ---------------- phase 2: bilinear sampling, float4 stores ----------
    const int l  = tid & 63;
    const int g  = u & 3;               // sample group
    const int ch = u >> 2;              // cc half: channels c = ch*128 + 4j + g
    const int z  = l >> 5;              // row parity
    const int q  = l & 31;              // wo quad index -> wo = 4q..4q+3
    const int ho = 2 * h + z;

    // coords for wo = 4q..4q+3
    const float4 cA = aux[2 * g + z][2 * q + 0];   // wo 4q, 4q+1
    const float4 cB = aux[2 * g + z][2 * q + 1];   // wo 4q+2, 4q+3

    const float ixs[4] = {cA.x, cA.z, cB.x, cB.z};
    const float iys[4] = {cA.y, cA.w, cB.y, cB.w};

    int   p00[4], p01[4], p10[4], p11[4];
    float w00[4], w01[4], w10[4], w11[4];
#pragma unroll
    for (int k = 0; k < 4; ++k) {
        const float x0f = floorf(ixs[k]);
        const float y0f = floorf(iys[k]);
        const float wx = ixs[k] - x0f;
        const float wy = iys[k] - y0f;
        int x0 = (int)x0f;
        int y0 = (int)y0f;
        x0 = max(0, min(x0, W_ - 1));
        y0 = max(0, min(y0, H_ - 1));
        const int x1 = min(x0 + 1, W_ - 1);
        const int y1 = min(y0 + 1, H_ - 1);
        w00[k] = (1.f - wy) * (1.f - wx);
        w01[k] = (1.f - wy) * wx;
        w10[k] = wy * (1.f - wx);
        w11[k] = wy * wx;
        p00[k] = y0 * W_ + x0;
        p01[k] = y0 * W_ + x1;
        p10[k] = y1 * W_ + x0;
        p11[k] = y1 * W_ + x1;
    }

    const float* xb = x + (size_t)b * C_ * HW_ + (size_t)(ch * 128 + g) * HW_;
    float* ob = out + (size_t)b * C_ * HOWO_ + (size_t)(ch * 128 + g) * HOWO_ +
                ho * WO_ + 4 * q;

#pragma unroll 4
    for (int j = 0; j < 32; ++j) {
        const float* pl = xb + (size_t)j * 4 * HW_;
        float val[4];
#pragma unroll
        for (int k = 0; k < 4; ++k) {
            val[k] = pl[p00[k]] * w00[k] + pl[p01[k]] * w01[k] +
                     pl[p10[k]] * w10[k] + pl[p11[k]] * w11[k];
        }
        f4v vec;
        vec.x = val[0]; vec.y = val[1]; vec.z = val[2]; vec.w = val[3];
        // wave-wide 1024 B contiguous NT store (rows 2h, 2h+1 adjacent)
        __builtin_nontemporal_store(vec,
            (f4v*)&ob[(size_t)j * 4 * HOWO_]);
    }
}

// ---------------------------------------------------------------------------
extern "C" void kernel_launch(void* const* d_in, const int* in_sizes, int n_in,
                              void* d_out, int out_size, void* d_ws, size_t ws_size,
                              hipStream_t stream) {
    const float* x       = (const float*)d_in[0];
    const float* w_off   = (const float*)d_in[1];
    const float* b_off   = (const float*)d_in[2];
    const float* w_scope = (const float*)d_in[3];
    const float* b_scope = (const float*)d_in[4];
    float* out = (float*)d_out;

    void* wsym = nullptr;
    (void)hipGetSymbolAddress(&wsym, HIP_SYMBOL(wconst));

    prep_kernel<<<dim3(40), 256, 0, stream>>>(w_off, w_scope, (float*)wsym);
    fused_kernel<<<dim3(B_ * H_), 512, 0, stream>>>(x, b_off, b_scope, out);
}

// Round 15
// 88.514 us; speedup vs baseline: 1.6389x; 1.6389x over previous
//
#include <hip/hip_runtime.h>
#include <math.h>

// Problem constants (B, C, H, W) = (16, 256, 64, 64), GROUPS=4, RATIO=2
#define B_   16
#define C_   256
#define H_   64
#define W_   64
#define G_   4
#define HO_  128
#define WO_  128
#define HW_  (H_ * W_)
#define HOWO_ (HO_ * WO_)

// Weights in constant address space -> uniform accesses compile to s_load.
__constant__ float wconst[8 * 32 * 40];   // 40 KB

// ---------------------------------------------------------------------------
// Prep: wcomb[u][i2][40] for wave u (v=u&3, hi=u>>2), channel i=64v+32hi+i2:
//   [0..31]  = w_off[o][i]                     o = 0..31
//   [32..39] = w_scope[v][j][32*hi + i2]       j = 0..7
// ---------------------------------------------------------------------------
__global__ __launch_bounds__(256) void prep_kernel(
    const float* __restrict__ w_off,    // (32, 256)
    const float* __restrict__ w_scope,  // (4, 8, 64)
    float* __restrict__ wout)           // = wconst backing store
{
    const int k = blockIdx.x * 256 + threadIdx.x;   // 10240 total
    if (k >= 8 * 32 * 40) return;
    const int q  = k % 40;
    const int r  = k / 40;
    const int i2 = r & 31;
    const int u  = r >> 5;
    const int v  = u & 3;
    const int hi = u >> 2;
    const int i  = 64 * v + 32 * hi + i2;
    float val;
    if (q < 32) val = w_off[q * 256 + i];
    else        val = w_scope[v * 512 + (q - 32) * 64 + 32 * hi + i2];
    wout[k] = val;
}

// ---------------------------------------------------------------------------
// Fused kernel (R11 structure; reduction LDS halved by slot reuse).
// red[4][8][64] float4 = 32 KB serves BOTH reduction rounds: round 1 hi-wave
// partials live in red[v] until lo wave v consumes them (only reader), then
// lo wave v overwrites red[v] with its round-2 sums. Total LDS 40 KB ->
// 4 blocks/CU x 8 waves = 32 waves/CU (2x the previous real occupancy).
// ---------------------------------------------------------------------------
__global__ __launch_bounds__(512, 8) void fused_kernel(
    const float* __restrict__ x,        // (B, 256, 64, 64)
    const float* __restrict__ b_off,    // (32,)
    const float* __restrict__ b_scope,  // (32,)
    float* __restrict__ out)            // (B, 256, 128, 128)
{
    __shared__ float4 red[4][8][64];    // [slot][chunk][pixel] 32 KB (reused)
    __shared__ float4 aux[8][64];       // scp partials, then coords; 8 KB

    const int tid = threadIdx.x;
    const int u   = __builtin_amdgcn_readfirstlane(tid >> 6);  // wave id
    const int w   = tid & 63;                                  // pixel in row

    // XCD-bijective swizzle: XCD k owns b in {2k, 2k+1}, all h.
    const int bid = ((blockIdx.x & 7) << 7) | (blockIdx.x >> 3);
    const int h   = bid & 63;
    const int b   = bid >> 6;

    const int v   = u & 3;              // group
    const int hi  = u >> 2;             // channel half

    const float* xq = x + (size_t)b * C_ * HW_ +
                      (size_t)(64 * v + 32 * hi) * HW_ + h * W_ + w;
    const int wbase0 = u * (32 * 40);   // uniform

    float offp[32];
    float scp[8];
#pragma unroll
    for (int j = 0; j < 32; ++j) offp[j] = 0.f;
#pragma unroll
    for (int j = 0; j < 8; ++j) scp[j] = 0.f;

#pragma unroll 4
    for (int i2 = 0; i2 < 32; ++i2) {
        const float xv = xq[(size_t)i2 * HW_];   // coalesced 256 B / wave
        const int wb = wbase0 + i2 * 40;         // uniform -> s_load from AS4
#pragma unroll
        for (int j = 0; j < 32; ++j) offp[j] += xv * wconst[wb + j];
#pragma unroll
        for (int j = 0; j < 8; ++j)  scp[j] += xv * wconst[wb + 32 + j];
    }

    // ---- round 1: high waves publish into red[v]; low waves absorb ----
    if (hi) {
#pragma unroll
        for (int j = 0; j < 8; ++j)
            red[v][j][w] = make_float4(offp[4 * j + 0], offp[4 * j + 1],
                                       offp[4 * j + 2], offp[4 * j + 3]);
        aux[2 * v + 0][w] = make_float4(scp[0], scp[1], scp[2], scp[3]);
        aux[2 * v + 1][w] = make_float4(scp[4], scp[5], scp[6], scp[7]);
    }
    __syncthreads();
    if (!hi) {
        // lo wave v is the ONLY reader of red[v]; read fully, then overwrite
#pragma unroll
        for (int j = 0; j < 8; ++j) {
            const float4 p = red[v][j][w];
            offp[4 * j + 0] += p.x; offp[4 * j + 1] += p.y;
            offp[4 * j + 2] += p.z; offp[4 * j + 3] += p.w;
        }
        const float4 s0 = aux[2 * v + 0][w];
        const float4 s1 = aux[2 * v + 1][w];
        scp[0] += s0.x; scp[1] += s0.y; scp[2] += s0.z; scp[3] += s0.w;
        scp[4] += s1.x; scp[5] += s1.y; scp[6] += s1.z; scp[7] += s1.w;
        // round 2 publish (slot reuse)
#pragma unroll
        for (int j = 0; j < 8; ++j)
            red[v][j][w] = make_float4(offp[4 * j + 0], offp[4 * j + 1],
                                       offp[4 * j + 2], offp[4 * j + 3]);
    }
    __syncthreads();
    if (!hi) {
        float4 a = make_float4(0.f, 0.f, 0.f, 0.f);
        float4 c = make_float4(0.f, 0.f, 0.f, 0.f);
#pragma unroll
        for (int tt = 0; tt < 4; ++tt) {
            const float4 pa = red[tt][2 * v + 0][w];
            const float4 pc = red[tt][2 * v + 1][w];
            a.x += pa.x; a.y += pa.y; a.z += pa.z; a.w += pa.w;
            c.x += pc.x; c.y += pc.y; c.z += pc.z; c.w += pc.w;
        }
        const float ao[8] = {a.x, a.y, a.z, a.w, c.x, c.y, c.z, c.w};
        float f[8];
#pragma unroll
        for (int j = 0; j < 8; ++j) {
            const float offv = ao[j] + b_off[8 * v + j];
            const float scv  = scp[j] + b_scope[8 * v + j];
            f[j] = offv * 0.5f / (1.f + expf(-scv));
        }
        // coords for group v: aux[2v+r1][w] = (ix0,iy0,ix1,iy1) for wo=2w,2w+1
#pragma unroll
        for (int r1 = 0; r1 < 2; ++r1) {
            const float hoF = (float)(2 * h + r1);
            float ix0 = ((float)(2 * w + 0) - 0.5f + f[2 * r1 + 0]) * 0.5f;
            float iy0 = (hoF - 0.5f + f[4 + 2 * r1 + 0]) * 0.5f;
            float ix1 = ((float)(2 * w + 1) - 0.5f + f[2 * r1 + 1]) * 0.5f;
            float iy1 = (hoF - 0.5f + f[4 + 2 * r1 + 1]) * 0.5f;
            ix0 = fminf(fmaxf(ix0, 0.f), (float)(W_ - 1));
            iy0 = fminf(fmaxf(iy0, 0.f), (float)(H_ - 1));
            ix1 = fminf(fmaxf(ix1, 0.f), (float)(W_ - 1));
            iy1 = fminf(fmaxf(iy1, 0.f), (float)(H_ - 1));
            aux[2 * v + r1][w] = make_float4(ix0, iy0, ix1, iy1);
        }
    }
    __syncthreads();

    // ---------------- phase 2: bilinear sampling (R11 verbatim) ----------
    const int wo = tid & 127;
    const int z  = (tid >> 7) & 1;
    const int gh = tid >> 8;            // group half
    const int ho = 2 * h + z;

    const float2* cbase = (const float2*)&aux[0][0];
    const float* xb0 = x + (size_t)b * C_ * HW_;
    float* ob0 = out + (size_t)b * C_ * HOWO_ + ho * WO_ + wo;

#pragma unroll
    for (int gg = 0; gg < 2; ++gg) {
        const int g = 2 * gh + gg;
        const float2 c = cbase[(g * 2 + z) * 128 + wo];
        const float ix = c.x, iy = c.y;

        const float x0f = floorf(ix);
        const float y0f = floorf(iy);
        const float wx = ix - x0f;
        const float wy = iy - y0f;
        int x0 = (int)x0f;
        int y0 = (int)y0f;
        x0 = max(0, min(x0, W_ - 1));
        y0 = max(0, min(y0, H_ - 1));
        const int x1 = min(x0 + 1, W_ - 1);
        const int y1 = min(y0 + 1, H_ - 1);

        const float w00 = (1.f - wy) * (1.f - wx);
        const float w01 = (1.f - wy) * wx;
        const float w10 = wy * (1.f - wx);
        const float w11 = wy * wx;

        const int p00 = y0 * W_ + x0;
        const int p01 = y0 * W_ + x1;
        const int p10 = y1 * W_ + x0;
        const int p11 = y1 * W_ + x1;

        const float* xb = xb0 + (size_t)g * HW_;
        float* ob = ob0 + (size_t)g * HOWO_;

#pragma unroll 4
        for (int cc = 0; cc < 64; ++cc) {
            const float* pl = xb + (size_t)cc * 4 * HW_;
            const float val = pl[p00] * w00 + pl[p01] * w01 +
                              pl[p10] * w10 + pl[p11] * w11;
            // out is write-once/never-read: nontemporal keeps L2/L3 for x
            __builtin_nontemporal_store(val, &ob[(size_t)cc * 4 * HOWO_]);
        }
    }
}

// ---------------------------------------------------------------------------
extern "C" void kernel_launch(void* const* d_in, const int* in_sizes, int n_in,
                              void* d_out, int out_size, void* d_ws, size_t ws_size,
                              hipStream_t stream) {
    const float* x       = (const float*)d_in[0];
    const float* w_off   = (const float*)d_in[1];
    const float* b_off   = (const float*)d_in[2];
    const float* w_scope = (const float*)d_in[3];
    const float* b_scope = (const float*)d_in[4];
    float* out = (float*)d_out;

    void* wsym = nullptr;
    (void)hipGetSymbolAddress(&wsym, HIP_SYMBOL(wconst));

    prep_kernel<<<dim3(40), 256, 0, stream>>>(w_off, w_scope, (float*)wsym);
    fused_kernel<<<dim3(B_ * H_), 512, 0, stream>>>(x, b_off, b_scope, out);
}